// Round 1
// baseline (345.249 us; speedup 1.0000x reference)
//
#include <hip/hip_runtime.h>
#include <cstdint>
#include <cstddef>

// Problem constants (match reference setup_inputs)
#define BB 32
#define SS 4096          // 2^12
#define FEAT_ 64
#define HID_ 32
#define NN 1024          // MAX_NODES

// ---------------------------------------------------------------------------
// Kernel 1: scatter-add flow_features into node_features[b, dst, :]
// one thread per (b, s, f4-chunk): coalesced float4 read + 4 atomicAdds.
// ---------------------------------------------------------------------------
__global__ void scatter_feat_kernel(const float* __restrict__ flow,
                                    const int* __restrict__ dst,
                                    float* __restrict__ nf) {
    int idx = blockIdx.x * blockDim.x + threadIdx.x;   // over B*S*16
    int bs  = idx >> 4;            // b*S + s
    int f4  = idx & 15;
    int b   = bs >> 12;            // S = 4096
    int d   = dst[bs];
    const float4 v = ((const float4*)flow)[idx];
    float* p = nf + (((size_t)b * NN + d) << 6) + (f4 << 2);
    atomicAdd(p + 0, v.x);
    atomicAdd(p + 1, v.y);
    atomicAdd(p + 2, v.z);
    atomicAdd(p + 3, v.w);
}

// ---------------------------------------------------------------------------
// Kernel 2: priority scatter into adjacency.
// Reference does: adj[b,src,dst] = w  (scatter 1, last index wins)
//            then adj[b,dst,src] = w  (scatter 2, overwrites scatter 1)
// Priority = s+1 for pass 1, S+s+1 for pass 2, stored as positive floats;
// atomicMax on int bits == float max for positive floats.
// ---------------------------------------------------------------------------
__global__ void scatter_prio_kernel(const int* __restrict__ src,
                                    const int* __restrict__ dst,
                                    float* __restrict__ adj) {
    int i = blockIdx.x * blockDim.x + threadIdx.x;  // b*S + s
    int s = i & (SS - 1);
    int b = i >> 12;
    int si = src[i], di = dst[i];
    int* base = (int*)(adj + (size_t)b * NN * NN);
    atomicMax(base + si * NN + di, __float_as_int((float)(s + 1)));
    atomicMax(base + di * NN + si, __float_as_int((float)(SS + s + 1)));
}

// ---------------------------------------------------------------------------
// Kernel 3: edge MLP -> weight w; claim cells whose stored priority matches.
// Exactly one winner per touched cell => deterministic last-write-wins.
// Priorities are >= 1.0f; weights are in (0,1) so bit patterns never collide.
// ---------------------------------------------------------------------------
__global__ void mlp_write_kernel(const int* __restrict__ src,
                                 const int* __restrict__ dst,
                                 const float* __restrict__ vol,
                                 const float* __restrict__ emb,
                                 const float* __restrict__ W1,
                                 const float* __restrict__ b1,
                                 const float* __restrict__ W2,
                                 const float* __restrict__ b2,
                                 float* __restrict__ adj) {
    int i = blockIdx.x * blockDim.x + threadIdx.x;  // b*S + s
    int s = i & (SS - 1);
    int b = i >> 12;
    int si = src[i], di = dst[i];

    float acc[HID_];
    #pragma unroll
    for (int j = 0; j < HID_; ++j) acc[j] = b1[j];

    // h = relu([emb[src]; emb[dst]] @ W1 + b1). W1 accesses are wave-uniform
    // (scalar-load friendly); emb rows are gathered, 256 B each, L2-resident.
    #pragma unroll
    for (int half = 0; half < 2; ++half) {
        const float* e = emb + ((half ? di : si) << 6);
        const float* w = W1 + half * 64 * HID_;
        for (int k = 0; k < 64; k += 4) {
            float4 v = *(const float4*)(e + k);
            #pragma unroll
            for (int j = 0; j < HID_; ++j) {
                float a = acc[j];
                a += v.x * w[(k + 0) * HID_ + j];
                a += v.y * w[(k + 1) * HID_ + j];
                a += v.z * w[(k + 2) * HID_ + j];
                a += v.w * w[(k + 3) * HID_ + j];
                acc[j] = a;
            }
        }
    }

    float dotv = b2[0];
    #pragma unroll
    for (int j = 0; j < HID_; ++j) dotv += fmaxf(acc[j], 0.0f) * W2[j];
    float edge_w = 1.0f / (1.0f + expf(-dotv));
    float vol_w  = 1.0f / (1.0f + expf(-vol[i] / 1000.0f));
    float wv = edge_w * vol_w;

    float* base = adj + (size_t)b * NN * NN;
    float* c1 = base + si * NN + di;
    float* c2 = base + di * NN + si;
    unsigned p1 = __float_as_uint((float)(s + 1));
    unsigned p2 = __float_as_uint((float)(SS + s + 1));
    if (__float_as_uint(*c1) == p1) *c1 = wv;
    if (__float_as_uint(*c2) == p2) *c2 = wv;
}

// ---------------------------------------------------------------------------
// Kernel 4: L2-normalize node_features rows. One wave (64 lanes) per row,
// lane = feature index; butterfly shuffle reduction over 64 lanes.
// ---------------------------------------------------------------------------
__global__ void normalize_kernel(float* __restrict__ nf) {
    int t = blockIdx.x * blockDim.x + threadIdx.x;  // over B*N*64
    int row  = t >> 6;
    int lane = t & 63;
    float* p = nf + (((size_t)row) << 6) + lane;
    float v = *p;
    float ss = v * v;
    #pragma unroll
    for (int off = 32; off > 0; off >>= 1) ss += __shfl_xor(ss, off, 64);
    float denom = fmaxf(sqrtf(ss), 1e-12f);
    *p = v / denom;
}

extern "C" void kernel_launch(void* const* d_in, const int* in_sizes, int n_in,
                              void* d_out, int out_size, void* d_ws, size_t ws_size,
                              hipStream_t stream) {
    const float* flow = (const float*)d_in[0];   // (B,S,64)
    const int*   src  = (const int*)d_in[1];     // (B,S)
    const int*   dst  = (const int*)d_in[2];     // (B,S)
    const float* vol  = (const float*)d_in[3];   // (B,S)
    const float* emb  = (const float*)d_in[4];   // (1024,64)
    const float* W1   = (const float*)d_in[5];   // (128,32)
    const float* b1   = (const float*)d_in[6];   // (32,)
    const float* W2   = (const float*)d_in[7];   // (32,1)
    const float* b2   = (const float*)d_in[8];   // (1,)

    float* nf  = (float*)d_out;                         // (B,N,64) = 2,097,152 floats
    float* adj = nf + (size_t)BB * NN * FEAT_;          // (B,N,N)  = 33,554,432 floats

    // d_out is poisoned 0xAA before every launch — zero it (graph-capturable).
    hipMemsetAsync(d_out, 0, (size_t)out_size * sizeof(float), stream);

    scatter_feat_kernel<<<(BB * SS * 16) / 256, 256, 0, stream>>>(flow, dst, nf);
    scatter_prio_kernel<<<(BB * SS) / 256, 256, 0, stream>>>(src, dst, adj);
    mlp_write_kernel<<<(BB * SS) / 256, 256, 0, stream>>>(src, dst, vol, emb,
                                                          W1, b1, W2, b2, adj);
    normalize_kernel<<<(BB * NN * 64) / 256, 256, 0, stream>>>(nf);
}

// Round 2
// 260.740 us; speedup vs baseline: 1.3241x; 1.3241x over previous
//
#include <hip/hip_runtime.h>
#include <cstdint>
#include <cstddef>

// Problem constants (match reference setup_inputs)
#define BB 32
#define SS 4096          // 2^12
#define FEAT_ 64
#define HID_ 32
#define NN 1024          // MAX_NODES

// ---------------------------------------------------------------------------
// Kernel 1: node_features via GATHER (no atomics) + fused L2-normalize.
// One block = 256 threads = 4 waves = 4 node rows of one batch.
// Block stages dst[b, 0..S) in LDS (16 KB); each wave scans it in 64
// ballot-iterations (lane-stride-1 LDS reads: 2-way bank aliasing, free).
// ~4 expected matches per row -> rare coalesced 256 B flow-row gathers.
// Row sum is accumulated in-register (deterministic s-order), L2-normalized
// via 64-lane butterfly, and written out directly — nf region needs no memset
// and no separate normalize kernel.
// ---------------------------------------------------------------------------
__global__ void node_feat_kernel(const float* __restrict__ flow,
                                 const int* __restrict__ dst,
                                 float* __restrict__ nf) {
    int row0 = blockIdx.x << 2;              // global row = b*NN + node
    int b = row0 >> 10;
    __shared__ int sdst[SS];

    const int4* g = (const int4*)(dst + (size_t)b * SS);
    int4* sd4 = (int4*)sdst;
    for (int i = threadIdx.x; i < SS / 4; i += 256) sd4[i] = g[i];
    __syncthreads();

    int wave = threadIdx.x >> 6;
    int lane = threadIdx.x & 63;
    int node = (row0 + wave) & (NN - 1);
    const float* fb = flow + ((size_t)b * SS << 6);

    float acc = 0.0f;
    for (int s0 = 0; s0 < SS; s0 += 64) {
        int d = sdst[s0 + lane];
        unsigned long long m = __ballot(d == node);
        while (m) {
            int bit = __ffsll((long long)m) - 1;
            m &= m - 1;
            acc += fb[((s0 + bit) << 6) + lane];   // coalesced 256 B row read
        }
    }

    float ss = acc * acc;
    #pragma unroll
    for (int off = 32; off > 0; off >>= 1) ss += __shfl_xor(ss, off, 64);
    float denom = fmaxf(sqrtf(ss), 1e-12f);
    nf[((size_t)(row0 + wave) << 6) + lane] = acc / denom;
}

// ---------------------------------------------------------------------------
// Kernel 2: priority scatter into adjacency.
// Reference does: adj[b,src,dst] = w  (scatter 1, last index wins)
//            then adj[b,dst,src] = w  (scatter 2, overwrites scatter 1)
// Priority = s+1 for pass 1, S+s+1 for pass 2, stored as positive floats;
// atomicMax on int bits == float max for positive floats.
// ---------------------------------------------------------------------------
__global__ void scatter_prio_kernel(const int* __restrict__ src,
                                    const int* __restrict__ dst,
                                    float* __restrict__ adj) {
    int i = blockIdx.x * blockDim.x + threadIdx.x;  // b*S + s
    int s = i & (SS - 1);
    int b = i >> 12;
    int si = src[i], di = dst[i];
    int* base = (int*)(adj + (size_t)b * NN * NN);
    atomicMax(base + si * NN + di, __float_as_int((float)(s + 1)));
    atomicMax(base + di * NN + si, __float_as_int((float)(SS + s + 1)));
}

// ---------------------------------------------------------------------------
// Kernel 3: edge MLP -> weight w; claim cells whose stored priority matches.
// Exactly one winner per touched cell => deterministic last-write-wins.
// Priorities are >= 1.0f; weights are in (0,1) so bit patterns never collide.
// ---------------------------------------------------------------------------
__global__ void mlp_write_kernel(const int* __restrict__ src,
                                 const int* __restrict__ dst,
                                 const float* __restrict__ vol,
                                 const float* __restrict__ emb,
                                 const float* __restrict__ W1,
                                 const float* __restrict__ b1,
                                 const float* __restrict__ W2,
                                 const float* __restrict__ b2,
                                 float* __restrict__ adj) {
    int i = blockIdx.x * blockDim.x + threadIdx.x;  // b*S + s
    int s = i & (SS - 1);
    int b = i >> 12;
    int si = src[i], di = dst[i];

    float acc[HID_];
    #pragma unroll
    for (int j = 0; j < HID_; ++j) acc[j] = b1[j];

    // h = relu([emb[src]; emb[dst]] @ W1 + b1). W1 accesses are wave-uniform
    // (scalar-load friendly); emb rows are gathered, 256 B each, L2-resident.
    #pragma unroll
    for (int half = 0; half < 2; ++half) {
        const float* e = emb + ((half ? di : si) << 6);
        const float* w = W1 + half * 64 * HID_;
        for (int k = 0; k < 64; k += 4) {
            float4 v = *(const float4*)(e + k);
            #pragma unroll
            for (int j = 0; j < HID_; ++j) {
                float a = acc[j];
                a += v.x * w[(k + 0) * HID_ + j];
                a += v.y * w[(k + 1) * HID_ + j];
                a += v.z * w[(k + 2) * HID_ + j];
                a += v.w * w[(k + 3) * HID_ + j];
                acc[j] = a;
            }
        }
    }

    float dotv = b2[0];
    #pragma unroll
    for (int j = 0; j < HID_; ++j) dotv += fmaxf(acc[j], 0.0f) * W2[j];
    float edge_w = 1.0f / (1.0f + expf(-dotv));
    float vol_w  = 1.0f / (1.0f + expf(-vol[i] / 1000.0f));
    float wv = edge_w * vol_w;

    float* base = adj + (size_t)b * NN * NN;
    float* c1 = base + si * NN + di;
    float* c2 = base + di * NN + si;
    unsigned p1 = __float_as_uint((float)(s + 1));
    unsigned p2 = __float_as_uint((float)(SS + s + 1));
    if (__float_as_uint(*c1) == p1) *c1 = wv;
    if (__float_as_uint(*c2) == p2) *c2 = wv;
}

extern "C" void kernel_launch(void* const* d_in, const int* in_sizes, int n_in,
                              void* d_out, int out_size, void* d_ws, size_t ws_size,
                              hipStream_t stream) {
    const float* flow = (const float*)d_in[0];   // (B,S,64)
    const int*   src  = (const int*)d_in[1];     // (B,S)
    const int*   dst  = (const int*)d_in[2];     // (B,S)
    const float* vol  = (const float*)d_in[3];   // (B,S)
    const float* emb  = (const float*)d_in[4];   // (1024,64)
    const float* W1   = (const float*)d_in[5];   // (128,32)
    const float* b1   = (const float*)d_in[6];   // (32,)
    const float* W2   = (const float*)d_in[7];   // (32,1)
    const float* b2   = (const float*)d_in[8];   // (1,)

    float* nf  = (float*)d_out;                         // (B,N,64) = 2,097,152 floats
    float* adj = nf + (size_t)BB * NN * FEAT_;          // (B,N,N)  = 33,554,432 floats

    // Only the adjacency needs zeroing; nf rows are fully written by the
    // gather kernel. (d_out is re-poisoned 0xAA before every timed launch.)
    hipMemsetAsync(adj, 0, (size_t)BB * NN * NN * sizeof(float), stream);

    scatter_prio_kernel<<<(BB * SS) / 256, 256, 0, stream>>>(src, dst, adj);
    mlp_write_kernel<<<(BB * SS) / 256, 256, 0, stream>>>(src, dst, vol, emb,
                                                          W1, b1, W2, b2, adj);
    node_feat_kernel<<<(BB * NN) / 4, 256, 0, stream>>>(flow, dst, nf);
}